// Round 12
// baseline (417.165 us; speedup 1.0000x reference)
//
#include <hip/hip_runtime.h>
#include <math.h>

#define Bb 2
#define Nn 32768
#define Cc 128
#define Ff 128
#define LL 4
#define SKN 128
#define PS 16448   // Spart plane stride (floats): breaks power-of-2 channel aliasing

typedef __attribute__((ext_vector_type(8))) short short8;
typedef __attribute__((ext_vector_type(4))) float float4v;
typedef __attribute__((ext_vector_type(2))) unsigned int uint2v;
typedef unsigned short ushort_t;
typedef unsigned int uint_t;

union frag_cast { short8 s; uint_t u[4]; };
union vec8 { float4v v[2]; float s[8]; };

__device__ inline uint_t asu(float f) { union { float f; uint_t u; } x; x.f = f; return x.u; }
__device__ inline float asf(uint_t u) { union { uint_t u; float f; } x; x.u = u; return x.f; }
// pack: low16 = bf16-trunc(v0), high16 = bf16-trunc(v1) -- single v_perm_b32
__device__ inline uint_t pack_hi(float v0, float v1) {
    return __builtin_amdgcn_perm(asu(v1), asu(v0), 0x07060302u);
}
// exact residual after bf16 truncation
__device__ inline float resid(float v) { return v - asf(asu(v) & 0xffff0000u); }

typedef __attribute__((address_space(1))) const uint_t guint;
typedef __attribute__((address_space(3))) uint_t luint;
__device__ inline void gload16(const uint_t* g, uint_t* l) {
    __builtin_amdgcn_global_load_lds((guint*)g, (luint*)l, 16, 0, 0);
}

// light barrier: LDS-only handoff (lgkmcnt drain, no vmcnt drain).
#define LBAR() asm volatile("s_waitcnt lgkmcnt(0)\n\ts_barrier" ::: "memory")
// counted barrier for fwd_lds (T4): each inter-barrier region issues exactly
// [gload_lds x2, X-loads x6] in pinned order -> vmcnt(6) drains only the DMA pair.
#define CBAR() asm volatile("s_waitcnt vmcnt(6) lgkmcnt(0)\n\ts_barrier" ::: "memory")

// ---------------- prep: transpose x,y -> [b][d][n] planes
__global__ __launch_bounds__(256) void prep_xt(const float* __restrict__ x,
                                               const float* __restrict__ y,
                                               float* __restrict__ xT,
                                               float* __restrict__ yT) {
    int i = blockIdx.x * 256 + threadIdx.x;        // b*Nn + n
    int b = i >> 15, n = i & 32767;
    const float* xp = x + (size_t)i * 3;
    const float* yp = y + (size_t)i * 3;
    size_t base = ((size_t)(b * 3) << 15) + n;
    xT[base] = xp[0]; xT[base + (1 << 15)] = xp[1]; xT[base + (2 << 15)] = xp[2];
    yT[base] = yp[0]; yT[base + (1 << 15)] = yp[1]; yT[base + (2 << 15)] = yp[2];
}

// ---------------- in projection -> packed bf16 hi/lo planes hfTh/hfTl[b][c][n-pair]
__global__ __launch_bounds__(256) void in_proj(const float* __restrict__ a,
                                               const float* __restrict__ w,
                                               const float* __restrict__ bias,
                                               uint_t* __restrict__ hfTh,
                                               uint_t* __restrict__ hfTl) {
    int idx = blockIdx.x * 256 + threadIdx.x;      // b*C*(N/2) + c*(N/2) + np
    int np = idx & 16383;
    int c = (idx >> 14) & 127;
    int b = idx >> 21;
    int n = np * 2;
    const float* ap = a + (((size_t)(b << 15)) + n) * 4;
    float s0 = bias[c], s1 = s0;
#pragma unroll
    for (int i = 0; i < 4; ++i) { s0 += ap[i] * w[i * Cc + c]; s1 += ap[4 + i] * w[i * Cc + c]; }
    hfTh[idx] = pack_hi(s0, s1);
    hfTl[idx] = pack_hi(resid(s0), resid(s1));
}

// ---------------- forward transform (layer 0 only), r8 version: consolidated,
// counted-vmcnt barriers. One 512-thread block per (sk, b). Grid (SKN, Bb).
__global__ __launch_bounds__(512, 2) void fwd_lds(const uint_t* __restrict__ hfTh,
                                                  const uint_t* __restrict__ hfTl,
                                                  const float* __restrict__ xT,
                                                  const float* __restrict__ freqs,
                                                  float* __restrict__ Spart) {
    __shared__ __align__(16) uint_t Ah_s[2][2048], Al_s[2][2048];   // 2 bufs x 128c x 16 dwords

    const int sk = blockIdx.x;
    const int b = blockIdx.y;
    const int tid = threadIdx.x, lane = tid & 63, wave = tid >> 6;
    const int h = wave & 1, wn = wave >> 1;        // wn in 0..3: f-quarter
    const int fr = lane & 15, kg = lane >> 4;

    float kx[2], ky[2], kz[2];
#pragma unroll
    for (int ni = 0; ni < 2; ++ni) {
        int f = wn * 32 + ni * 16 + fr;
        kx[ni] = freqs[f * 3 + 0];
        ky[ni] = freqs[f * 3 + 1];
        kz[ni] = freqs[f * 3 + 2];
    }

    const float* xb = xT + ((size_t)(b * 3) << 15);
    const int srow = wave * 16 + (lane >> 2);      // 0..127
    const size_t gbase = ((size_t)(b * 128 + srow) << 14) + (size_t)((lane & 3) * 4);
    const int npair0 = sk * 128;

    float4v acc[8][2];
#pragma unroll
    for (int mi = 0; mi < 8; ++mi)
#pragma unroll
        for (int ni = 0; ni < 2; ++ni) acc[mi][ni] = (float4v){0.f, 0.f, 0.f, 0.f};

    vec8 X0[2], X1[2], X2[2];
    gload16(hfTh + gbase + npair0, &Ah_s[0][wave * 256]);
    gload16(hfTl + gbase + npair0, &Al_s[0][wave * 256]);
    __builtin_amdgcn_sched_barrier(0);
    {
        const int nbase = sk * 256 + kg * 8;
        X0[0].v[0] = *(const float4v*)(xb + nbase);
        X0[0].v[1] = *(const float4v*)(xb + nbase + 4);
        X1[0].v[0] = *(const float4v*)(xb + (1 << 15) + nbase);
        X1[0].v[1] = *(const float4v*)(xb + (1 << 15) + nbase + 4);
        X2[0].v[0] = *(const float4v*)(xb + (2 << 15) + nbase);
        X2[0].v[1] = *(const float4v*)(xb + (2 << 15) + nbase + 4);
    }

#pragma unroll
    for (int kt = 0; kt < 8; ++kt) {
        const int cur = kt & 1, nxt = cur ^ 1;
        CBAR();
        if (kt < 7) {
            gload16(hfTh + gbase + npair0 + (kt + 1) * 16, &Ah_s[nxt][wave * 256]);
            gload16(hfTl + gbase + npair0 + (kt + 1) * 16, &Al_s[nxt][wave * 256]);
            __builtin_amdgcn_sched_barrier(0);
            const int nbase2 = sk * 256 + (kt + 1) * 32 + kg * 8;
            X0[nxt].v[0] = *(const float4v*)(xb + nbase2);
            X0[nxt].v[1] = *(const float4v*)(xb + nbase2 + 4);
            X1[nxt].v[0] = *(const float4v*)(xb + (1 << 15) + nbase2);
            X1[nxt].v[1] = *(const float4v*)(xb + (1 << 15) + nbase2 + 4);
            X2[nxt].v[0] = *(const float4v*)(xb + (2 << 15) + nbase2);
            X2[nxt].v[1] = *(const float4v*)(xb + (2 << 15) + nbase2 + 4);
        }
        float r[16], tv[16];
#pragma unroll
        for (int ni = 0; ni < 2; ++ni)
#pragma unroll
            for (int q = 0; q < 4; ++q) {
                float rv0 = X0[cur].s[2 * q] * kx[ni] + X1[cur].s[2 * q] * ky[ni] + X2[cur].s[2 * q] * kz[ni];
                float rv1 = X0[cur].s[2 * q + 1] * kx[ni] + X1[cur].s[2 * q + 1] * ky[ni] + X2[cur].s[2 * q + 1] * kz[ni];
                r[ni * 8 + 2 * q] = __builtin_amdgcn_fractf(rv0);
                r[ni * 8 + 2 * q + 1] = __builtin_amdgcn_fractf(rv1);
            }
        if (h) {
#pragma unroll
            for (int i = 0; i < 16; ++i) tv[i] = __builtin_amdgcn_sinf(r[i]);
        } else {
#pragma unroll
            for (int i = 0; i < 16; ++i) tv[i] = __builtin_amdgcn_cosf(r[i]);
        }
        frag_cast bhf[2], blf[2];
#pragma unroll
        for (int ni = 0; ni < 2; ++ni)
#pragma unroll
            for (int q = 0; q < 4; ++q) {
                float v0 = tv[ni * 8 + 2 * q], v1 = tv[ni * 8 + 2 * q + 1];
                bhf[ni].u[q] = pack_hi(v0, v1);
                blf[ni].u[q] = pack_hi(resid(v0), resid(v1));
            }
#pragma unroll
        for (int mi = 0; mi < 8; ++mi) {
            frag_cast ah, al;
            ah.s = *(const short8*)&Ah_s[cur][(mi * 16 + fr) * 16 + kg * 4];
            al.s = *(const short8*)&Al_s[cur][(mi * 16 + fr) * 16 + kg * 4];
#pragma unroll
            for (int ni = 0; ni < 2; ++ni) {
                acc[mi][ni] = __builtin_amdgcn_mfma_f32_16x16x32_bf16(ah.s, bhf[ni].s, acc[mi][ni], 0, 0, 0);
                acc[mi][ni] = __builtin_amdgcn_mfma_f32_16x16x32_bf16(ah.s, blf[ni].s, acc[mi][ni], 0, 0, 0);
                acc[mi][ni] = __builtin_amdgcn_mfma_f32_16x16x32_bf16(al.s, bhf[ni].s, acc[mi][ni], 0, 0, 0);
            }
        }
    }

    float* op = Spart + (size_t)((b * 2 + h) * SKN + sk) * PS;
#pragma unroll
    for (int mi = 0; mi < 8; ++mi)
#pragma unroll
        for (int ni = 0; ni < 2; ++ni)
#pragma unroll
            for (int r2 = 0; r2 < 4; ++r2) {
                int c = mi * 16 + kg * 4 + r2;
                int f = wn * 32 + ni * 16 + fr;
                op[c * 128 + f] = acc[mi][ni][r2];
            }
}

// ---------------- FUSED inverse(l) + forward(l+1), 16-wave: grid (128, Bb), 1024 thr,
// 8 phases of 32 n. Same traffic/barriers/LDS as the r9 512-thr version (timed 330.8),
// but 4 waves/SIMD inside each barrier phase (was 2) to hide LDS/trig/MFMA latency --
// per-phase work was ~6x smaller than measured phase time (latency-bound at 2 waves/SIMD).
// inv roles: og=wv&7 (o-group AND kt share), mh=wv>>3 (m-half).
// fwd roles: h=wv&1, wf=(wv>>1)&3 (f-quarter), fh=wv>>3 (mi-half; fwd trig dup x2).
__global__ __launch_bounds__(1024, 4) void inv_fwd(const uint_t* __restrict__ Gh,
                                                   const uint_t* __restrict__ Gl,
                                                   const float* __restrict__ xT,
                                                   const float* __restrict__ fI,   // freqs layer l
                                                   const float* __restrict__ fF,   // freqs layer l+1
                                                   float* __restrict__ Spart) {
    __shared__ float kxs[128], kys[128], kzs[128];       // inv freqs (revolutions)
    __shared__ __align__(16) float Xs[3][256];           // x chunk, 3 KB
    __shared__ __align__(16) uint_t Ah_s[4096], Al_s[4096]; // [mi2][kt8][lane64][q4], 16+16 KB
    __shared__ __align__(16) uint_t Hh_s[2560], Hl_s[2560]; // hf tile [c128][row-stride 20], 10+10 KB
    const int chunk = blockIdx.x, b = blockIdx.y;
    const int tid = threadIdx.x, lane = tid & 63, wv = tid >> 6;   // wv 0..15
    const int fr = lane & 15, kg = lane >> 4;
    const int og = wv & 7, mh = wv >> 3;                 // inv roles
    const int h = wv & 1, wf = (wv >> 1) & 3, fh = wv >> 3;  // fwd roles
    const int n0 = chunk * 256;

    if (tid < 128) {
        kxs[tid] = fI[tid * 3 + 0];
        kys[tid] = fI[tid * 3 + 1];
        kzs[tid] = fI[tid * 3 + 2];
    }
    // stage x chunk (768 floats)
    if (tid < 768) {
        int d = tid >> 8, nn = tid & 255;
        Xs[d][nn] = xT[((size_t)(b * 3 + d) << 15) + n0 + nn];
    }

    // inv B-frags: wave's 16-o group (og), all 8 kt (16 frags)
    frag_cast bh[8], bl[8];
#pragma unroll
    for (int kt = 0; kt < 8; ++kt) {
        size_t gi = ((size_t)(b * 128 + og * 16 + fr)) * 128 + kt * 16 + kg * 4;
        bh[kt].s = *(const short8*)(Gh + gi);
        bl[kt].s = *(const short8*)(Gl + gi);
    }

    // fwd per-lane next-layer freqs
    float kxf[2], kyf[2], kzf[2];
#pragma unroll
    for (int ni = 0; ni < 2; ++ni) {
        int f = wf * 32 + ni * 16 + fr;
        kxf[ni] = fF[f * 3 + 0];
        kyf[ni] = fF[f * 3 + 1];
        kzf[ni] = fF[f * 3 + 2];
    }

    float4v accF[4][2];
#pragma unroll
    for (int mi4 = 0; mi4 < 4; ++mi4)
#pragma unroll
        for (int ni = 0; ni < 2; ++ni) accF[mi4][ni] = (float4v){0.f, 0.f, 0.f, 0.f};

    __syncthreads();                                   // Xs + kxs visible

    for (int p = 0; p < 8; ++p) {
        const int nsub = p * 32;

        // ---- (a) inv trig: wave's (kt=og, mi2=mh) share: ONE frag pair per lane
        {
            const int kt = og;
            float4v kxv = *(const float4v*)&kxs[kt * 16 + kg * 4];
            float4v kyv = *(const float4v*)&kys[kt * 16 + kg * 4];
            float4v kzv = *(const float4v*)&kzs[kt * 16 + kg * 4];
            float px = Xs[0][nsub + mh * 16 + fr];
            float py = Xs[1][nsub + mh * 16 + fr];
            float pz = Xs[2][nsub + mh * 16 + fr];
            frag_cast ah, al;
#pragma unroll
            for (int q = 0; q < 4; ++q) {
                float rev = px * kxv[q] + py * kyv[q] + pz * kzv[q];
                float rr = __builtin_amdgcn_fractf(rev);
                float cv = __builtin_amdgcn_cosf(rr);
                float sv = __builtin_amdgcn_sinf(rr);
                ah.u[q] = pack_hi(cv, sv);
                al.u[q] = pack_hi(resid(cv), resid(sv));
            }
            *(short8*)&Ah_s[((mh * 8 + kt) * 64 + lane) * 4] = ah.s;
            *(short8*)&Al_s[((mh * 8 + kt) * 64 + lane) * 4] = al.s;
        }
        LBAR();                                        // trig A-frags staged (16 waves cover all)

        // ---- (b) inv MFMA for mi2=mh only (24 MFMA, 3 chains of 8) + gelu -> H tile
        {
            float4v ahh = (float4v){0.f, 0.f, 0.f, 0.f};
            float4v ahl = (float4v){0.f, 0.f, 0.f, 0.f};
            float4v alh = (float4v){0.f, 0.f, 0.f, 0.f};
#pragma unroll
            for (int kt = 0; kt < 8; ++kt) {
                frag_cast ah, al;
                ah.s = *(const short8*)&Ah_s[((mh * 8 + kt) * 64 + lane) * 4];
                al.s = *(const short8*)&Al_s[((mh * 8 + kt) * 64 + lane) * 4];
                ahh = __builtin_amdgcn_mfma_f32_16x16x32_bf16(ah.s, bh[kt].s, ahh, 0, 0, 0);
                ahl = __builtin_amdgcn_mfma_f32_16x16x32_bf16(ah.s, bl[kt].s, ahl, 0, 0, 0);
                alh = __builtin_amdgcn_mfma_f32_16x16x32_bf16(al.s, bh[kt].s, alh, 0, 0, 0);
            }
            float g[4];
#pragma unroll
            for (int r2 = 0; r2 < 4; ++r2) {
                float v = ahh[r2] + (ahl[r2] + alh[r2]);
                float u2 = 1.5957691216057308f * (v + 0.044715f * v * v * v);
                float t = 1.0f - 2.0f / (1.0f + __expf(u2));
                g[r2] = 0.5f * v * (1.0f + t);
            }
            int row = og * 16 + fr;
            uint2v hv = { pack_hi(g[0], g[1]), pack_hi(g[2], g[3]) };
            uint2v lv = { pack_hi(resid(g[0]), resid(g[1])), pack_hi(resid(g[2]), resid(g[3])) };
            *(uint2v*)&Hh_s[row * 20 + mh * 8 + kg * 2] = hv;
            *(uint2v*)&Hl_s[row * 20 + mh * 8 + kg * 2] = lv;
        }
        LBAR();                                        // H tile staged (and A-frag reads done)

        // ---- (c) fwd trig + MFMA: this wave's mi-half (4 of 8 c-row tiles)
        {
            vec8 x0, x1, x2;
            x0.v[0] = *(const float4v*)&Xs[0][nsub + kg * 8];
            x0.v[1] = *(const float4v*)&Xs[0][nsub + kg * 8 + 4];
            x1.v[0] = *(const float4v*)&Xs[1][nsub + kg * 8];
            x1.v[1] = *(const float4v*)&Xs[1][nsub + kg * 8 + 4];
            x2.v[0] = *(const float4v*)&Xs[2][nsub + kg * 8];
            x2.v[1] = *(const float4v*)&Xs[2][nsub + kg * 8 + 4];
            float r[16], tv[16];
#pragma unroll
            for (int ni = 0; ni < 2; ++ni)
#pragma unroll
                for (int q = 0; q < 4; ++q) {
                    float rv0 = x0.s[2 * q] * kxf[ni] + x1.s[2 * q] * kyf[ni] + x2.s[2 * q] * kzf[ni];
                    float rv1 = x0.s[2 * q + 1] * kxf[ni] + x1.s[2 * q + 1] * kyf[ni] + x2.s[2 * q + 1] * kzf[ni];
                    r[ni * 8 + 2 * q] = __builtin_amdgcn_fractf(rv0);
                    r[ni * 8 + 2 * q + 1] = __builtin_amdgcn_fractf(rv1);
                }
            if (h) {
#pragma unroll
                for (int i = 0; i < 16; ++i) tv[i] = __builtin_amdgcn_sinf(r[i]);
            } else {
#pragma unroll
                for (int i = 0; i < 16; ++i) tv[i] = __builtin_amdgcn_cosf(r[i]);
            }
            frag_cast bhf[2], blf[2];
#pragma unroll
            for (int ni = 0; ni < 2; ++ni)
#pragma unroll
                for (int q = 0; q < 4; ++q) {
                    float v0 = tv[ni * 8 + 2 * q], v1 = tv[ni * 8 + 2 * q + 1];
                    bhf[ni].u[q] = pack_hi(v0, v1);
                    blf[ni].u[q] = pack_hi(resid(v0), resid(v1));
                }
#pragma unroll
            for (int mi4 = 0; mi4 < 4; ++mi4) {
                const int mi = fh * 4 + mi4;
                frag_cast ah, al;
                ah.s = *(const short8*)&Hh_s[(mi * 16 + fr) * 20 + kg * 4];
                al.s = *(const short8*)&Hl_s[(mi * 16 + fr) * 20 + kg * 4];
#pragma unroll
                for (int ni = 0; ni < 2; ++ni) {
                    accF[mi4][ni] = __builtin_amdgcn_mfma_f32_16x16x32_bf16(ah.s, bhf[ni].s, accF[mi4][ni], 0, 0, 0);
                    accF[mi4][ni] = __builtin_amdgcn_mfma_f32_16x16x32_bf16(ah.s, blf[ni].s, accF[mi4][ni], 0, 0, 0);
                    accF[mi4][ni] = __builtin_amdgcn_mfma_f32_16x16x32_bf16(al.s, bhf[ni].s, accF[mi4][ni], 0, 0, 0);
                }
            }
        }
        LBAR();                                        // H reads done -> next phase may overwrite
    }

    // Spart epilogue (identical coverage: h from wv&1, c rows via fh)
    float* op = Spart + (size_t)((b * 2 + h) * SKN + chunk) * PS;
#pragma unroll
    for (int mi4 = 0; mi4 < 4; ++mi4)
#pragma unroll
        for (int ni = 0; ni < 2; ++ni)
#pragma unroll
            for (int r2 = 0; r2 < 4; ++r2) {
                int c = (fh * 4 + mi4) * 16 + kg * 4 + r2;
                int f = wf * 32 + ni * 16 + fr;
                op[c * 128 + f] = accF[mi4][ni][r2];
            }
}

// ---------------- reduce split-K partials, two-stage in-block (1024 blocks)
__global__ __launch_bounds__(256) void reduce_kernel(const float* __restrict__ Spart,
                                                     float* __restrict__ S) {
    __shared__ float red[4][64];
    const int chunk = blockIdx.x, bh = blockIdx.y;
    const int tid = threadIdx.x;
    const int cfl = tid & 63, q = tid >> 6;
    const float* p = Spart + (size_t)bh * SKN * PS + (size_t)(q * 32) * PS + chunk * 64 + cfl;
    float s = 0.0f;
#pragma unroll 8
    for (int k = 0; k < 32; ++k) s += p[(size_t)k * PS];
    red[q][cfl] = s;
    __syncthreads();
    if (tid < 64) {
        float t = red[0][tid] + red[1][tid] + red[2][tid] + red[3][tid];
        S[bh * 16384 + chunk * 64 + tid] = t;
    }
}

// ---------------- channel mixing -> packed bf16 hi/lo G planes (512 blocks, W read once)
__global__ __launch_bounds__(256) void mix_kernel(const float* __restrict__ S,
                                                  const float* __restrict__ Wre,
                                                  const float* __restrict__ Wim,
                                                  uint_t* __restrict__ Gh,
                                                  uint_t* __restrict__ Gl) {
    __shared__ float Stile[4][128][16];            // [b*2+h][c][f-local], 32 KB
    const int ot = blockIdx.x;                     // 64 tiles of 2 o
    const int ft = blockIdx.y;                     // 8 tiles of 16 f
    const int tid = threadIdx.x;
    const int fl = tid & 15, ol = (tid >> 4) & 1, cg = tid >> 5;   // cg: 8-way c-split
    const int o = ot * 2 + ol, f0 = ft * 16;

    for (int i = tid; i < 8192; i += 256) {
        int bh = i >> 11, c = (i >> 4) & 127, ff = i & 15;
        Stile[bh][c][ff] = S[(size_t)bh * 16384 + c * 128 + f0 + ff];
    }
    __syncthreads();

    float g0 = 0.f, g1 = 0.f, g2 = 0.f, g3 = 0.f;  // gre_b0, gmi_b0, gre_b1, gmi_b1
#pragma unroll 4
    for (int c = cg * 16; c < cg * 16 + 16; ++c) {
        float wr = Wre[((size_t)(c * 128 + o)) * 128 + f0 + fl];
        float wi = Wim[((size_t)(c * 128 + o)) * 128 + f0 + fl];
        float sc0 = Stile[0][c][fl], ss0 = Stile[1][c][fl];
        float sc1 = Stile[2][c][fl], ss1 = Stile[3][c][fl];
        g0 += sc0 * wr + ss0 * wi;  g1 += ss0 * wr - sc0 * wi;
        g2 += sc1 * wr + ss1 * wi;  g3 += ss1 * wr - sc1 * wi;
    }
    __syncthreads();
    float4v* rp = (float4v*)Stile;                 // reuse LDS: 8 cg x 32 (ol,fl)
    rp[cg * 32 + ol * 16 + fl] = (float4v){g0, g1, g2, g3};
    __syncthreads();
    if (tid < 32) {
        int tol = tid >> 4, tfl = tid & 15;
        float4v r = rp[tid];
#pragma unroll
        for (int j = 1; j < 8; ++j) r += rp[j * 32 + tid];
        const float invN = 1.0f / (float)Nn;
        float gre0 = r[0] * invN, gmi0 = r[1] * invN;
        float gre1 = r[2] * invN, gmi1 = r[3] * invN;
        int oo = ot * 2 + tol;
        Gh[(0 * 128 + oo) * 128 + f0 + tfl] = pack_hi(gre0, gmi0);
        Gl[(0 * 128 + oo) * 128 + f0 + tfl] = pack_hi(resid(gre0), resid(gmi0));
        Gh[(1 * 128 + oo) * 128 + f0 + tfl] = pack_hi(gre1, gmi1);
        Gl[(1 * 128 + oo) * 128 + f0 + tfl] = pack_hi(resid(gre1), resid(gmi1));
    }
}

// ---------------- final inverse evaluation + gelu + FUSED out-projection (r11 version).
template <int LAST>
__global__ __launch_bounds__(512, 4) void inv_reg(const uint_t* __restrict__ Gh,
                                                  const uint_t* __restrict__ Gl,
                                                  const float* __restrict__ ptsT,
                                                  const float* __restrict__ freqs,
                                                  uint_t* __restrict__ hfTh,
                                                  uint_t* __restrict__ hfTl,
                                                  const float* __restrict__ ow,
                                                  const float* __restrict__ ob,
                                                  float* __restrict__ u) {
    __shared__ __align__(16) float kxs[128], kys[128], kzs[128];
    __shared__ __align__(16) uint_t Ah_s[4096];    // [mi2][kt8][lane64][q4] dwords = 16 KB
    __shared__ __align__(16) uint_t Al_s[4096];    // 16 KB
    __shared__ float redo[8][32][2];               // LAST: per-wave o-partials, 2 KB
    const int nt = blockIdx.x, b = blockIdx.y;
    const int tid = threadIdx.x, lane = tid & 63, wn = tid >> 6;   // wn 0..7
    const int fr = lane & 15, kg = lane >> 4;

    if (tid < 128) {                               // raw k (revolutions)
        kxs[tid] = freqs[tid * 3 + 0];
        kys[tid] = freqs[tid * 3 + 1];
        kzs[tid] = freqs[tid * 3 + 2];
    }

    frag_cast bh[8], bl[8];
#pragma unroll
    for (int kt = 0; kt < 8; ++kt) {
        size_t gi = ((size_t)(b * 128 + wn * 16 + fr)) * 128 + kt * 16 + kg * 4;
        bh[kt].s = *(const short8*)(Gh + gi);
        bl[kt].s = *(const short8*)(Gl + gi);
    }

    float w0v = 0.f, w1v = 0.f;
    if (LAST) {
        int o = wn * 16 + fr;
        w0v = ow[o * 2 + 0];
        w1v = ow[o * 2 + 1];
    }

    const float* pb = ptsT + ((size_t)(b * 3) << 15);
    const int n0 = nt * 64;

    float px[4], py[4], pz[4];
#pragma unroll
    for (int m = 0; m < 4; ++m) {
        int n = n0 + m * 16 + fr;
        px[m] = pb[n]; py[m] = pb[(1 << 15) + n]; pz[m] = pb[(2 << 15) + n];
    }

    __syncthreads();

#pragma unroll
    for (int ph = 0; ph < 2; ++ph) {
        {
            const int kt = wn;
            float4v kxv = *(const float4v*)&kxs[kt * 16 + kg * 4];
            float4v kyv = *(const float4v*)&kys[kt * 16 + kg * 4];
            float4v kzv = *(const float4v*)&kzs[kt * 16 + kg * 4];
#pragma unroll
            for (int mi2 = 0; mi2 < 2; ++mi2) {
                const int m = ph * 2 + mi2;
                frag_cast ah, al;
#pragma unroll
                for (int q = 0; q < 4; ++q) {
                    float rev = px[m] * kxv[q] + py[m] * kyv[q] + pz[m] * kzv[q];
                    float rr = __builtin_amdgcn_fractf(rev);
                    float cv = __builtin_amdgcn_cosf(rr);
                    float sv = __builtin_amdgcn_sinf(rr);
                    ah.u[q] = pack_hi(cv, sv);
                    al.u[q] = pack_hi(resid(cv), resid(sv));
                }
                *(short8*)&Ah_s[((mi2 * 8 + kt) * 64 + lane) * 4] = ah.s;
                *(short8*)&Al_s[((mi2 * 8 + kt) * 64 + lane) * 4] = al.s;
            }
        }
        LBAR();

        float4v ahh[2], ahl[2], alh[2];
#pragma unroll
        for (int mi2 = 0; mi2 < 2; ++mi2) {
            ahh[mi2] = (float4v){0.f, 0.f, 0.f, 0.f};
            ahl[mi2] = (float4v){0.f, 0.f, 0.f, 0.f};
            alh[mi2] = (float4v){0.f, 0.f, 0.f, 0.f};
        }
#pragma unroll
        for (int kt = 0; kt < 8; ++kt) {
#pragma unroll
            for (int mi2 = 0; mi2 < 2; ++mi2) {
                frag_cast ah, al;
                ah.s = *(const short8*)&Ah_s[((mi2 * 8 + kt) * 64 + lane) * 4];
                al.s = *(const short8*)&Al_s[((mi2 * 8 + kt) * 64 + lane) * 4];
                ahh[mi2] = __builtin_amdgcn_mfma_f32_16x16x32_bf16(ah.s, bh[kt].s, ahh[mi2], 0, 0, 0);
                ahl[mi2] = __builtin_amdgcn_mfma_f32_16x16x32_bf16(ah.s, bl[kt].s, ahl[mi2], 0, 0, 0);
                alh[mi2] = __builtin_amdgcn_mfma_f32_16x16x32_bf16(al.s, bh[kt].s, alh[mi2], 0, 0, 0);
            }
        }
        LBAR();

        float ps[2][2][4];
        if (LAST) {
#pragma unroll
            for (int mi2 = 0; mi2 < 2; ++mi2)
#pragma unroll
                for (int j = 0; j < 2; ++j)
#pragma unroll
                    for (int r2 = 0; r2 < 4; ++r2) ps[mi2][j][r2] = 0.f;
        }
#pragma unroll
        for (int mi2 = 0; mi2 < 2; ++mi2) {
            const int m = ph * 2 + mi2;
            float g[4];
#pragma unroll
            for (int r2 = 0; r2 < 4; ++r2) {
                float v = ahh[mi2][r2] + (ahl[mi2][r2] + alh[mi2][r2]);
                float u2 = 1.5957691216057308f * (v + 0.044715f * v * v * v);
                float t = 1.0f - 2.0f / (1.0f + __expf(u2));
                g[r2] = 0.5f * v * (1.0f + t);
            }
            if (!LAST) {
                int o = wn * 16 + fr;
                int nb = n0 + m * 16 + kg * 4;
                size_t di = ((size_t)(b * 128 + o) << 14) + (nb >> 1);
                uint2v hv = { pack_hi(g[0], g[1]), pack_hi(g[2], g[3]) };
                uint2v lv = { pack_hi(resid(g[0]), resid(g[1])), pack_hi(resid(g[2]), resid(g[3])) };
                *(uint2v*)(hfTh + di) = hv;
                *(uint2v*)(hfTl + di) = lv;
            } else {
#pragma unroll
                for (int r2 = 0; r2 < 4; ++r2) {
                    ps[mi2][0][r2] += g[r2] * w0v;
                    ps[mi2][1][r2] += g[r2] * w1v;
                }
            }
        }

        if (LAST) {
#pragma unroll
            for (int mi2 = 0; mi2 < 2; ++mi2)
#pragma unroll
                for (int j = 0; j < 2; ++j)
#pragma unroll
                    for (int r2 = 0; r2 < 4; ++r2) {
                        float v = ps[mi2][j][r2];
                        v += __shfl_xor(v, 1);
                        v += __shfl_xor(v, 2);
                        v += __shfl_xor(v, 4);
                        v += __shfl_xor(v, 8);
                        ps[mi2][j][r2] = v;
                    }
            if (fr == 0) {
#pragma unroll
                for (int mi2 = 0; mi2 < 2; ++mi2)
#pragma unroll
                    for (int r2 = 0; r2 < 4; ++r2) {
                        redo[wn][mi2 * 16 + kg * 4 + r2][0] = ps[mi2][0][r2];
                        redo[wn][mi2 * 16 + kg * 4 + r2][1] = ps[mi2][1][r2];
                    }
            }
            LBAR();
            if (tid < 64) {
                int nl = tid >> 1, j = tid & 1;
                float val = ob[j];
#pragma unroll
                for (int w8 = 0; w8 < 8; ++w8) val += redo[w8][nl][j];
                u[((size_t)((b << 15) + n0 + ph * 32 + nl)) * 2 + j] = val;
            }
            LBAR();
        }
    }
}

extern "C" void kernel_launch(void* const* d_in, const int* in_sizes, int n_in,
                              void* d_out, int out_size, void* d_ws, size_t ws_size,
                              hipStream_t stream) {
    const float* a        = (const float*)d_in[0];
    const float* x        = (const float*)d_in[1];
    const float* y        = (const float*)d_in[2];
    const float* fc_in_w  = (const float*)d_in[3];
    const float* fc_in_b  = (const float*)d_in[4];
    const float* freqs    = (const float*)d_in[5];
    const float* w_real   = (const float*)d_in[6];
    const float* w_imag   = (const float*)d_in[7];
    const float* fc_out_w = (const float*)d_in[8];
    const float* fc_out_b = (const float*)d_in[9];
    float* out = (float*)d_out;

    uint_t* ws    = (uint_t*)d_ws;
    uint_t* hfTh  = ws;                                        // B*C*N/2 = 4,194,304 dwords
    uint_t* hfTl  = hfTh + (size_t)Bb * Cc * Nn / 2;           // 4,194,304
    float*  Spart = (float*)(hfTl + (size_t)Bb * Cc * Nn / 2); // B*2*SKN*PS = 8,421,376 floats
    float*  S     = Spart + (size_t)Bb * 2 * SKN * PS;         // 65,536
    uint_t* Gh    = (uint_t*)(S + (size_t)Bb * 2 * Cc * Ff);   // 32,768
    uint_t* Gl    = Gh + (size_t)Bb * Cc * Ff;                 // 32,768
    float*  xT    = (float*)(Gl + (size_t)Bb * Cc * Ff);       // 196,608 floats
    float*  yT    = xT + (size_t)Bb * 3 * Nn;                  // 196,608

    prep_xt<<<(Bb * Nn) / 256, 256, 0, stream>>>(x, y, xT, yT);
    in_proj<<<(Bb * Cc * Nn / 2) / 256, 256, 0, stream>>>(a, fc_in_w, fc_in_b, hfTh, hfTl);

    // layer 0 forward (from in_proj's hfT), 128 split-K slots
    fwd_lds<<<dim3(SKN, Bb), 512, 0, stream>>>(hfTh, hfTl, xT, freqs, Spart);
    reduce_kernel<<<dim3(256, 4), 256, 0, stream>>>(Spart, S);
    mix_kernel<<<dim3(64, 8), 256, 0, stream>>>(S, w_real, w_imag, Gh, Gl);

    // layers 0..2: fused inverse(l) + forward(l+1); hfT never touches global
    for (int l = 0; l < LL - 1; ++l) {
        const float* kI  = freqs  + (size_t)l * Ff * 3;
        const float* kF  = freqs  + (size_t)(l + 1) * Ff * 3;
        const float* Wre = w_real + (size_t)(l + 1) * Cc * Cc * Ff;
        const float* Wim = w_imag + (size_t)(l + 1) * Cc * Cc * Ff;

        inv_fwd<<<dim3(128, Bb), 1024, 0, stream>>>(Gh, Gl, xT, kI, kF, Spart);
        reduce_kernel<<<dim3(256, 4), 256, 0, stream>>>(Spart, S);
        mix_kernel<<<dim3(64, 8), 256, 0, stream>>>(S, Wre, Wim, Gh, Gl);
    }

    // final inverse at y + fused out-projection
    inv_reg<1><<<dim3(512, Bb), 512, 0, stream>>>(Gh, Gl, yT, freqs + (size_t)(LL - 1) * Ff * 3,
                                                  hfTh, hfTl, fc_out_w, fc_out_b, out);
}

// Round 13
// 330.092 us; speedup vs baseline: 1.2638x; 1.2638x over previous
//
#include <hip/hip_runtime.h>
#include <math.h>

#define Bb 2
#define Nn 32768
#define Cc 128
#define Ff 128
#define LL 4
#define SKN 128
#define PS 16448   // Spart plane stride (floats): breaks power-of-2 channel aliasing

typedef __attribute__((ext_vector_type(8))) short short8;
typedef __attribute__((ext_vector_type(4))) float float4v;
typedef __attribute__((ext_vector_type(2))) unsigned int uint2v;
typedef unsigned short ushort_t;
typedef unsigned int uint_t;

union frag_cast { short8 s; uint_t u[4]; };
union vec8 { float4v v[2]; float s[8]; };

__device__ inline uint_t asu(float f) { union { float f; uint_t u; } x; x.f = f; return x.u; }
__device__ inline float asf(uint_t u) { union { uint_t u; float f; } x; x.u = u; return x.f; }
// pack: low16 = bf16-trunc(v0), high16 = bf16-trunc(v1) -- single v_perm_b32
__device__ inline uint_t pack_hi(float v0, float v1) {
    return __builtin_amdgcn_perm(asu(v1), asu(v0), 0x07060302u);
}
// exact residual after bf16 truncation
__device__ inline float resid(float v) { return v - asf(asu(v) & 0xffff0000u); }

typedef __attribute__((address_space(1))) const uint_t guint;
typedef __attribute__((address_space(3))) uint_t luint;
__device__ inline void gload16(const uint_t* g, uint_t* l) {
    __builtin_amdgcn_global_load_lds((guint*)g, (luint*)l, 16, 0, 0);
}

// light barrier: LDS-only handoff (lgkmcnt drain, no vmcnt drain).
#define LBAR() asm volatile("s_waitcnt lgkmcnt(0)\n\ts_barrier" ::: "memory")
// counted barrier for fwd_lds (T4): each inter-barrier region issues exactly
// [gload_lds x2, X-loads x6] in pinned order -> vmcnt(6) drains only the DMA pair.
#define CBAR() asm volatile("s_waitcnt vmcnt(6) lgkmcnt(0)\n\ts_barrier" ::: "memory")

// ---------------- prep: transpose x,y -> [b][d][n] planes
__global__ __launch_bounds__(256) void prep_xt(const float* __restrict__ x,
                                               const float* __restrict__ y,
                                               float* __restrict__ xT,
                                               float* __restrict__ yT) {
    int i = blockIdx.x * 256 + threadIdx.x;        // b*Nn + n
    int b = i >> 15, n = i & 32767;
    const float* xp = x + (size_t)i * 3;
    const float* yp = y + (size_t)i * 3;
    size_t base = ((size_t)(b * 3) << 15) + n;
    xT[base] = xp[0]; xT[base + (1 << 15)] = xp[1]; xT[base + (2 << 15)] = xp[2];
    yT[base] = yp[0]; yT[base + (1 << 15)] = yp[1]; yT[base + (2 << 15)] = yp[2];
}

// ---------------- in projection -> packed bf16 hi/lo planes hfTh/hfTl[b][c][n-pair]
__global__ __launch_bounds__(256) void in_proj(const float* __restrict__ a,
                                               const float* __restrict__ w,
                                               const float* __restrict__ bias,
                                               uint_t* __restrict__ hfTh,
                                               uint_t* __restrict__ hfTl) {
    int idx = blockIdx.x * 256 + threadIdx.x;      // b*C*(N/2) + c*(N/2) + np
    int np = idx & 16383;
    int c = (idx >> 14) & 127;
    int b = idx >> 21;
    int n = np * 2;
    const float* ap = a + (((size_t)(b << 15)) + n) * 4;
    float s0 = bias[c], s1 = s0;
#pragma unroll
    for (int i = 0; i < 4; ++i) { s0 += ap[i] * w[i * Cc + c]; s1 += ap[4 + i] * w[i * Cc + c]; }
    hfTh[idx] = pack_hi(s0, s1);
    hfTl[idx] = pack_hi(resid(s0), resid(s1));
}

// ---------------- forward transform (layer 0 only), r8 version: consolidated,
// counted-vmcnt barriers. One 512-thread block per (sk, b). Grid (SKN, Bb).
__global__ __launch_bounds__(512, 2) void fwd_lds(const uint_t* __restrict__ hfTh,
                                                  const uint_t* __restrict__ hfTl,
                                                  const float* __restrict__ xT,
                                                  const float* __restrict__ freqs,
                                                  float* __restrict__ Spart) {
    __shared__ __align__(16) uint_t Ah_s[2][2048], Al_s[2][2048];   // 2 bufs x 128c x 16 dwords

    const int sk = blockIdx.x;
    const int b = blockIdx.y;
    const int tid = threadIdx.x, lane = tid & 63, wave = tid >> 6;
    const int h = wave & 1, wn = wave >> 1;        // wn in 0..3: f-quarter
    const int fr = lane & 15, kg = lane >> 4;

    float kx[2], ky[2], kz[2];
#pragma unroll
    for (int ni = 0; ni < 2; ++ni) {
        int f = wn * 32 + ni * 16 + fr;
        kx[ni] = freqs[f * 3 + 0];
        ky[ni] = freqs[f * 3 + 1];
        kz[ni] = freqs[f * 3 + 2];
    }

    const float* xb = xT + ((size_t)(b * 3) << 15);
    const int srow = wave * 16 + (lane >> 2);      // 0..127
    const size_t gbase = ((size_t)(b * 128 + srow) << 14) + (size_t)((lane & 3) * 4);
    const int npair0 = sk * 128;

    float4v acc[8][2];
#pragma unroll
    for (int mi = 0; mi < 8; ++mi)
#pragma unroll
        for (int ni = 0; ni < 2; ++ni) acc[mi][ni] = (float4v){0.f, 0.f, 0.f, 0.f};

    vec8 X0[2], X1[2], X2[2];
    gload16(hfTh + gbase + npair0, &Ah_s[0][wave * 256]);
    gload16(hfTl + gbase + npair0, &Al_s[0][wave * 256]);
    __builtin_amdgcn_sched_barrier(0);
    {
        const int nbase = sk * 256 + kg * 8;
        X0[0].v[0] = *(const float4v*)(xb + nbase);
        X0[0].v[1] = *(const float4v*)(xb + nbase + 4);
        X1[0].v[0] = *(const float4v*)(xb + (1 << 15) + nbase);
        X1[0].v[1] = *(const float4v*)(xb + (1 << 15) + nbase + 4);
        X2[0].v[0] = *(const float4v*)(xb + (2 << 15) + nbase);
        X2[0].v[1] = *(const float4v*)(xb + (2 << 15) + nbase + 4);
    }

#pragma unroll
    for (int kt = 0; kt < 8; ++kt) {
        const int cur = kt & 1, nxt = cur ^ 1;
        CBAR();
        if (kt < 7) {
            gload16(hfTh + gbase + npair0 + (kt + 1) * 16, &Ah_s[nxt][wave * 256]);
            gload16(hfTl + gbase + npair0 + (kt + 1) * 16, &Al_s[nxt][wave * 256]);
            __builtin_amdgcn_sched_barrier(0);
            const int nbase2 = sk * 256 + (kt + 1) * 32 + kg * 8;
            X0[nxt].v[0] = *(const float4v*)(xb + nbase2);
            X0[nxt].v[1] = *(const float4v*)(xb + nbase2 + 4);
            X1[nxt].v[0] = *(const float4v*)(xb + (1 << 15) + nbase2);
            X1[nxt].v[1] = *(const float4v*)(xb + (1 << 15) + nbase2 + 4);
            X2[nxt].v[0] = *(const float4v*)(xb + (2 << 15) + nbase2);
            X2[nxt].v[1] = *(const float4v*)(xb + (2 << 15) + nbase2 + 4);
        }
        float r[16], tv[16];
#pragma unroll
        for (int ni = 0; ni < 2; ++ni)
#pragma unroll
            for (int q = 0; q < 4; ++q) {
                float rv0 = X0[cur].s[2 * q] * kx[ni] + X1[cur].s[2 * q] * ky[ni] + X2[cur].s[2 * q] * kz[ni];
                float rv1 = X0[cur].s[2 * q + 1] * kx[ni] + X1[cur].s[2 * q + 1] * ky[ni] + X2[cur].s[2 * q + 1] * kz[ni];
                r[ni * 8 + 2 * q] = __builtin_amdgcn_fractf(rv0);
                r[ni * 8 + 2 * q + 1] = __builtin_amdgcn_fractf(rv1);
            }
        if (h) {
#pragma unroll
            for (int i = 0; i < 16; ++i) tv[i] = __builtin_amdgcn_sinf(r[i]);
        } else {
#pragma unroll
            for (int i = 0; i < 16; ++i) tv[i] = __builtin_amdgcn_cosf(r[i]);
        }
        frag_cast bhf[2], blf[2];
#pragma unroll
        for (int ni = 0; ni < 2; ++ni)
#pragma unroll
            for (int q = 0; q < 4; ++q) {
                float v0 = tv[ni * 8 + 2 * q], v1 = tv[ni * 8 + 2 * q + 1];
                bhf[ni].u[q] = pack_hi(v0, v1);
                blf[ni].u[q] = pack_hi(resid(v0), resid(v1));
            }
#pragma unroll
        for (int mi = 0; mi < 8; ++mi) {
            frag_cast ah, al;
            ah.s = *(const short8*)&Ah_s[cur][(mi * 16 + fr) * 16 + kg * 4];
            al.s = *(const short8*)&Al_s[cur][(mi * 16 + fr) * 16 + kg * 4];
#pragma unroll
            for (int ni = 0; ni < 2; ++ni) {
                acc[mi][ni] = __builtin_amdgcn_mfma_f32_16x16x32_bf16(ah.s, bhf[ni].s, acc[mi][ni], 0, 0, 0);
                acc[mi][ni] = __builtin_amdgcn_mfma_f32_16x16x32_bf16(ah.s, blf[ni].s, acc[mi][ni], 0, 0, 0);
                acc[mi][ni] = __builtin_amdgcn_mfma_f32_16x16x32_bf16(al.s, bhf[ni].s, acc[mi][ni], 0, 0, 0);
            }
        }
    }

    float* op = Spart + (size_t)((b * 2 + h) * SKN + sk) * PS;
#pragma unroll
    for (int mi = 0; mi < 8; ++mi)
#pragma unroll
        for (int ni = 0; ni < 2; ++ni)
#pragma unroll
            for (int r2 = 0; r2 < 4; ++r2) {
                int c = mi * 16 + kg * 4 + r2;
                int f = wn * 32 + ni * 16 + fr;
                op[c * 128 + f] = acc[mi][ni][r2];
            }
}

// ---------------- FUSED inverse(l) + forward(l+1): grid (128, Bb), 512 thr, 8 phases
// of 32 n (r9 structure, timed-best; r10 grid-split and r12 wave-split both flipped the
// kernel memory-bound -- cache-subsidized, parallelism must not grow the working set).
// inv-MFMA accumulators split 3-way (hh/hl/lh -> 6 independent 8-deep chains).
__global__ __launch_bounds__(512, 2) void inv_fwd(const uint_t* __restrict__ Gh,
                                                  const uint_t* __restrict__ Gl,
                                                  const float* __restrict__ xT,
                                                  const float* __restrict__ fI,   // freqs layer l
                                                  const float* __restrict__ fF,   // freqs layer l+1
                                                  float* __restrict__ Spart) {
    __shared__ float kxs[128], kys[128], kzs[128];       // inv freqs (revolutions)
    __shared__ __align__(16) float Xs[3][256];           // x chunk, 3 KB
    __shared__ __align__(16) uint_t Ah_s[4096], Al_s[4096]; // [mi2][kt8][lane64][q4], 16+16 KB
    __shared__ __align__(16) uint_t Hh_s[2560], Hl_s[2560]; // hf tile [c128][row-stride 20], 10+10 KB
    const int chunk = blockIdx.x, b = blockIdx.y;
    const int tid = threadIdx.x, lane = tid & 63, wn = tid >> 6;   // wn 0..7
    const int fr = lane & 15, kg = lane >> 4;
    const int h = wn & 1, wf = wn >> 1;                  // fwd roles
    const int n0 = chunk * 256;

    if (tid < 128) {
        kxs[tid] = fI[tid * 3 + 0];
        kys[tid] = fI[tid * 3 + 1];
        kzs[tid] = fI[tid * 3 + 2];
    }
    // stage x chunk (768 floats)
    for (int i = tid; i < 768; i += 512) {
        int d = i >> 8, nn = i & 255;
        Xs[d][nn] = xT[((size_t)(b * 3 + d) << 15) + n0 + nn];
    }

    // inv B-frags: wave's 16-o block, all 8 kt (16 frags)
    frag_cast bh[8], bl[8];
#pragma unroll
    for (int kt = 0; kt < 8; ++kt) {
        size_t gi = ((size_t)(b * 128 + wn * 16 + fr)) * 128 + kt * 16 + kg * 4;
        bh[kt].s = *(const short8*)(Gh + gi);
        bl[kt].s = *(const short8*)(Gl + gi);
    }

    // fwd per-lane next-layer freqs
    float kxf[2], kyf[2], kzf[2];
#pragma unroll
    for (int ni = 0; ni < 2; ++ni) {
        int f = wf * 32 + ni * 16 + fr;
        kxf[ni] = fF[f * 3 + 0];
        kyf[ni] = fF[f * 3 + 1];
        kzf[ni] = fF[f * 3 + 2];
    }

    float4v accF[8][2];
#pragma unroll
    for (int mi = 0; mi < 8; ++mi)
#pragma unroll
        for (int ni = 0; ni < 2; ++ni) accF[mi][ni] = (float4v){0.f, 0.f, 0.f, 0.f};

    __syncthreads();                                   // Xs + kxs visible

    for (int p = 0; p < 8; ++p) {
        const int nsub = p * 32;

        // ---- (a) inv trig: wave's kt share, 2 m-tiles of 16 n
        {
            const int kt = wn;
            float4v kxv = *(const float4v*)&kxs[kt * 16 + kg * 4];
            float4v kyv = *(const float4v*)&kys[kt * 16 + kg * 4];
            float4v kzv = *(const float4v*)&kzs[kt * 16 + kg * 4];
#pragma unroll
            for (int mi2 = 0; mi2 < 2; ++mi2) {
                float px = Xs[0][nsub + mi2 * 16 + fr];
                float py = Xs[1][nsub + mi2 * 16 + fr];
                float pz = Xs[2][nsub + mi2 * 16 + fr];
                frag_cast ah, al;
#pragma unroll
                for (int q = 0; q < 4; ++q) {
                    float rev = px * kxv[q] + py * kyv[q] + pz * kzv[q];
                    float rr = __builtin_amdgcn_fractf(rev);
                    float cv = __builtin_amdgcn_cosf(rr);
                    float sv = __builtin_amdgcn_sinf(rr);
                    ah.u[q] = pack_hi(cv, sv);
                    al.u[q] = pack_hi(resid(cv), resid(sv));
                }
                *(short8*)&Ah_s[((mi2 * 8 + kt) * 64 + lane) * 4] = ah.s;
                *(short8*)&Al_s[((mi2 * 8 + kt) * 64 + lane) * 4] = al.s;
            }
        }
        LBAR();                                        // trig A-frags staged

        // ---- (b) inv MFMA (3-way split acc) + gelu -> pack into H tile
        {
            float4v ahh[2], ahl[2], alh[2];
#pragma unroll
            for (int mi2 = 0; mi2 < 2; ++mi2) {
                ahh[mi2] = (float4v){0.f, 0.f, 0.f, 0.f};
                ahl[mi2] = (float4v){0.f, 0.f, 0.f, 0.f};
                alh[mi2] = (float4v){0.f, 0.f, 0.f, 0.f};
            }
#pragma unroll
            for (int kt = 0; kt < 8; ++kt) {
#pragma unroll
                for (int mi2 = 0; mi2 < 2; ++mi2) {
                    frag_cast ah, al;
                    ah.s = *(const short8*)&Ah_s[((mi2 * 8 + kt) * 64 + lane) * 4];
                    al.s = *(const short8*)&Al_s[((mi2 * 8 + kt) * 64 + lane) * 4];
                    ahh[mi2] = __builtin_amdgcn_mfma_f32_16x16x32_bf16(ah.s, bh[kt].s, ahh[mi2], 0, 0, 0);
                    ahl[mi2] = __builtin_amdgcn_mfma_f32_16x16x32_bf16(ah.s, bl[kt].s, ahl[mi2], 0, 0, 0);
                    alh[mi2] = __builtin_amdgcn_mfma_f32_16x16x32_bf16(al.s, bh[kt].s, alh[mi2], 0, 0, 0);
                }
            }
#pragma unroll
            for (int mi2 = 0; mi2 < 2; ++mi2) {
                float g[4];
#pragma unroll
                for (int r2 = 0; r2 < 4; ++r2) {
                    float v = ahh[mi2][r2] + (ahl[mi2][r2] + alh[mi2][r2]);
                    float u2 = 1.5957691216057308f * (v + 0.044715f * v * v * v);
                    float t = 1.0f - 2.0f / (1.0f + __expf(u2));
                    g[r2] = 0.5f * v * (1.0f + t);
                }
                int row = wn * 16 + fr;
                uint2v hv = { pack_hi(g[0], g[1]), pack_hi(g[2], g[3]) };
                uint2v lv = { pack_hi(resid(g[0]), resid(g[1])), pack_hi(resid(g[2]), resid(g[3])) };
                *(uint2v*)&Hh_s[row * 20 + mi2 * 8 + kg * 2] = hv;
                *(uint2v*)&Hl_s[row * 20 + mi2 * 8 + kg * 2] = lv;
            }
        }
        LBAR();                                        // H tile staged (and A-frag reads done)

        // ---- (c) fwd trig + MFMA over this 32-n K-step
        {
            vec8 x0, x1, x2;
            x0.v[0] = *(const float4v*)&Xs[0][nsub + kg * 8];
            x0.v[1] = *(const float4v*)&Xs[0][nsub + kg * 8 + 4];
            x1.v[0] = *(const float4v*)&Xs[1][nsub + kg * 8];
            x1.v[1] = *(const float4v*)&Xs[1][nsub + kg * 8 + 4];
            x2.v[0] = *(const float4v*)&Xs[2][nsub + kg * 8];
            x2.v[1] = *(const float4v*)&Xs[2][nsub + kg * 8 + 4];
            float r[16], tv[16];
#pragma unroll
            for (int ni = 0; ni < 2; ++ni)
#pragma unroll
                for (int q = 0; q < 4; ++q) {
                    float rv0 = x0.s[2 * q] * kxf[ni] + x1.s[2 * q] * kyf[ni] + x2.s[2 * q] * kzf[ni];
                    float rv1 = x0.s[2 * q + 1] * kxf[ni] + x1.s[2 * q + 1] * kyf[ni] + x2.s[2 * q + 1] * kzf[ni];
                    r[ni * 8 + 2 * q] = __builtin_amdgcn_fractf(rv0);
                    r[ni * 8 + 2 * q + 1] = __builtin_amdgcn_fractf(rv1);
                }
            if (h) {
#pragma unroll
                for (int i = 0; i < 16; ++i) tv[i] = __builtin_amdgcn_sinf(r[i]);
            } else {
#pragma unroll
                for (int i = 0; i < 16; ++i) tv[i] = __builtin_amdgcn_cosf(r[i]);
            }
            frag_cast bhf[2], blf[2];
#pragma unroll
            for (int ni = 0; ni < 2; ++ni)
#pragma unroll
                for (int q = 0; q < 4; ++q) {
                    float v0 = tv[ni * 8 + 2 * q], v1 = tv[ni * 8 + 2 * q + 1];
                    bhf[ni].u[q] = pack_hi(v0, v1);
                    blf[ni].u[q] = pack_hi(resid(v0), resid(v1));
                }
#pragma unroll
            for (int mi = 0; mi < 8; ++mi) {
                frag_cast ah, al;
                ah.s = *(const short8*)&Hh_s[(mi * 16 + fr) * 20 + kg * 4];
                al.s = *(const short8*)&Hl_s[(mi * 16 + fr) * 20 + kg * 4];
#pragma unroll
                for (int ni = 0; ni < 2; ++ni) {
                    accF[mi][ni] = __builtin_amdgcn_mfma_f32_16x16x32_bf16(ah.s, bhf[ni].s, accF[mi][ni], 0, 0, 0);
                    accF[mi][ni] = __builtin_amdgcn_mfma_f32_16x16x32_bf16(ah.s, blf[ni].s, accF[mi][ni], 0, 0, 0);
                    accF[mi][ni] = __builtin_amdgcn_mfma_f32_16x16x32_bf16(al.s, bhf[ni].s, accF[mi][ni], 0, 0, 0);
                }
            }
        }
        LBAR();                                        // H reads done -> next phase may overwrite
    }

    // Spart epilogue (identical to fwd_lds)
    float* op = Spart + (size_t)((b * 2 + h) * SKN + chunk) * PS;
#pragma unroll
    for (int mi = 0; mi < 8; ++mi)
#pragma unroll
        for (int ni = 0; ni < 2; ++ni)
#pragma unroll
            for (int r2 = 0; r2 < 4; ++r2) {
                int c = mi * 16 + kg * 4 + r2;
                int f = wf * 32 + ni * 16 + fr;
                op[c * 128 + f] = accF[mi][ni][r2];
            }
}

// ---------------- reduce split-K partials, two-stage in-block (1024 blocks)
__global__ __launch_bounds__(256) void reduce_kernel(const float* __restrict__ Spart,
                                                     float* __restrict__ S) {
    __shared__ float red[4][64];
    const int chunk = blockIdx.x, bh = blockIdx.y;
    const int tid = threadIdx.x;
    const int cfl = tid & 63, q = tid >> 6;
    const float* p = Spart + (size_t)bh * SKN * PS + (size_t)(q * 32) * PS + chunk * 64 + cfl;
    float s = 0.0f;
#pragma unroll 8
    for (int k = 0; k < 32; ++k) s += p[(size_t)k * PS];
    red[q][cfl] = s;
    __syncthreads();
    if (tid < 64) {
        float t = red[0][tid] + red[1][tid] + red[2][tid] + red[3][tid];
        S[bh * 16384 + chunk * 64 + tid] = t;
    }
}

// ---------------- channel mixing -> packed bf16 hi/lo G planes (512 blocks, W read once)
__global__ __launch_bounds__(256) void mix_kernel(const float* __restrict__ S,
                                                  const float* __restrict__ Wre,
                                                  const float* __restrict__ Wim,
                                                  uint_t* __restrict__ Gh,
                                                  uint_t* __restrict__ Gl) {
    __shared__ float Stile[4][128][16];            // [b*2+h][c][f-local], 32 KB
    const int ot = blockIdx.x;                     // 64 tiles of 2 o
    const int ft = blockIdx.y;                     // 8 tiles of 16 f
    const int tid = threadIdx.x;
    const int fl = tid & 15, ol = (tid >> 4) & 1, cg = tid >> 5;   // cg: 8-way c-split
    const int o = ot * 2 + ol, f0 = ft * 16;

    for (int i = tid; i < 8192; i += 256) {
        int bh = i >> 11, c = (i >> 4) & 127, ff = i & 15;
        Stile[bh][c][ff] = S[(size_t)bh * 16384 + c * 128 + f0 + ff];
    }
    __syncthreads();

    float g0 = 0.f, g1 = 0.f, g2 = 0.f, g3 = 0.f;  // gre_b0, gmi_b0, gre_b1, gmi_b1
#pragma unroll 4
    for (int c = cg * 16; c < cg * 16 + 16; ++c) {
        float wr = Wre[((size_t)(c * 128 + o)) * 128 + f0 + fl];
        float wi = Wim[((size_t)(c * 128 + o)) * 128 + f0 + fl];
        float sc0 = Stile[0][c][fl], ss0 = Stile[1][c][fl];
        float sc1 = Stile[2][c][fl], ss1 = Stile[3][c][fl];
        g0 += sc0 * wr + ss0 * wi;  g1 += ss0 * wr - sc0 * wi;
        g2 += sc1 * wr + ss1 * wi;  g3 += ss1 * wr - sc1 * wi;
    }
    __syncthreads();
    float4v* rp = (float4v*)Stile;                 // reuse LDS: 8 cg x 32 (ol,fl)
    rp[cg * 32 + ol * 16 + fl] = (float4v){g0, g1, g2, g3};
    __syncthreads();
    if (tid < 32) {
        int tol = tid >> 4, tfl = tid & 15;
        float4v r = rp[tid];
#pragma unroll
        for (int j = 1; j < 8; ++j) r += rp[j * 32 + tid];
        const float invN = 1.0f / (float)Nn;
        float gre0 = r[0] * invN, gmi0 = r[1] * invN;
        float gre1 = r[2] * invN, gmi1 = r[3] * invN;
        int oo = ot * 2 + tol;
        Gh[(0 * 128 + oo) * 128 + f0 + tfl] = pack_hi(gre0, gmi0);
        Gl[(0 * 128 + oo) * 128 + f0 + tfl] = pack_hi(resid(gre0), resid(gmi0));
        Gh[(1 * 128 + oo) * 128 + f0 + tfl] = pack_hi(gre1, gmi1);
        Gl[(1 * 128 + oo) * 128 + f0 + tfl] = pack_hi(resid(gre1), resid(gmi1));
    }
}

// ---------------- final inverse evaluation + gelu + FUSED out-projection (r7 structure,
// 3-way split inv accumulators). 512 thr / block, 64 n x 128 o; each wave owns 16 o.
template <int LAST>
__global__ __launch_bounds__(512, 4) void inv_reg(const uint_t* __restrict__ Gh,
                                                  const uint_t* __restrict__ Gl,
                                                  const float* __restrict__ ptsT,
                                                  const float* __restrict__ freqs,
                                                  uint_t* __restrict__ hfTh,
                                                  uint_t* __restrict__ hfTl,
                                                  const float* __restrict__ ow,
                                                  const float* __restrict__ ob,
                                                  float* __restrict__ u) {
    __shared__ __align__(16) float kxs[128], kys[128], kzs[128];
    __shared__ __align__(16) uint_t Ah_s[4096];    // [mi2][kt8][lane64][q4] dwords = 16 KB
    __shared__ __align__(16) uint_t Al_s[4096];    // 16 KB
    __shared__ float redo[8][32][2];               // LAST: per-wave o-partials, 2 KB
    const int nt = blockIdx.x, b = blockIdx.y;
    const int tid = threadIdx.x, lane = tid & 63, wn = tid >> 6;   // wn 0..7
    const int fr = lane & 15, kg = lane >> 4;

    if (tid < 128) {                               // raw k (revolutions)
        kxs[tid] = freqs[tid * 3 + 0];
        kys[tid] = freqs[tid * 3 + 1];
        kzs[tid] = freqs[tid * 3 + 2];
    }

    frag_cast bh[8], bl[8];
#pragma unroll
    for (int kt = 0; kt < 8; ++kt) {
        size_t gi = ((size_t)(b * 128 + wn * 16 + fr)) * 128 + kt * 16 + kg * 4;
        bh[kt].s = *(const short8*)(Gh + gi);
        bl[kt].s = *(const short8*)(Gl + gi);
    }

    float w0v = 0.f, w1v = 0.f;
    if (LAST) {
        int o = wn * 16 + fr;
        w0v = ow[o * 2 + 0];
        w1v = ow[o * 2 + 1];
    }

    const float* pb = ptsT + ((size_t)(b * 3) << 15);
    const int n0 = nt * 64;

    float px[4], py[4], pz[4];
#pragma unroll
    for (int m = 0; m < 4; ++m) {
        int n = n0 + m * 16 + fr;
        px[m] = pb[n]; py[m] = pb[(1 << 15) + n]; pz[m] = pb[(2 << 15) + n];
    }

    __syncthreads();

#pragma unroll
    for (int ph = 0; ph < 2; ++ph) {
        {
            const int kt = wn;
            float4v kxv = *(const float4v*)&kxs[kt * 16 + kg * 4];
            float4v kyv = *(const float4v*)&kys[kt * 16 + kg * 4];
            float4v kzv = *(const float4v*)&kzs[kt * 16 + kg * 4];
#pragma unroll
            for (int mi2 = 0; mi2 < 2; ++mi2) {
                const int m = ph * 2 + mi2;
                frag_cast ah, al;
#pragma unroll
                for (int q = 0; q < 4; ++q) {
                    float rev = px[m] * kxv[q] + py[m] * kyv[q] + pz[m] * kzv[q];
                    float rr = __builtin_amdgcn_fractf(rev);
                    float cv = __builtin_amdgcn_cosf(rr);
                    float sv = __builtin_amdgcn_sinf(rr);
                    ah.u[q] = pack_hi(cv, sv);
                    al.u[q] = pack_hi(resid(cv), resid(sv));
                }
                *(short8*)&Ah_s[((mi2 * 8 + kt) * 64 + lane) * 4] = ah.s;
                *(short8*)&Al_s[((mi2 * 8 + kt) * 64 + lane) * 4] = al.s;
            }
        }
        LBAR();

        float4v ahh[2], ahl[2], alh[2];
#pragma unroll
        for (int mi2 = 0; mi2 < 2; ++mi2) {
            ahh[mi2] = (float4v){0.f, 0.f, 0.f, 0.f};
            ahl[mi2] = (float4v){0.f, 0.f, 0.f, 0.f};
            alh[mi2] = (float4v){0.f, 0.f, 0.f, 0.f};
        }
#pragma unroll
        for (int kt = 0; kt < 8; ++kt) {
#pragma unroll
            for (int mi2 = 0; mi2 < 2; ++mi2) {
                frag_cast ah, al;
                ah.s = *(const short8*)&Ah_s[((mi2 * 8 + kt) * 64 + lane) * 4];
                al.s = *(const short8*)&Al_s[((mi2 * 8 + kt) * 64 + lane) * 4];
                ahh[mi2] = __builtin_amdgcn_mfma_f32_16x16x32_bf16(ah.s, bh[kt].s, ahh[mi2], 0, 0, 0);
                ahl[mi2] = __builtin_amdgcn_mfma_f32_16x16x32_bf16(ah.s, bl[kt].s, ahl[mi2], 0, 0, 0);
                alh[mi2] = __builtin_amdgcn_mfma_f32_16x16x32_bf16(al.s, bh[kt].s, alh[mi2], 0, 0, 0);
            }
        }
        LBAR();

        float ps[2][2][4];
        if (LAST) {
#pragma unroll
            for (int mi2 = 0; mi2 < 2; ++mi2)
#pragma unroll
                for (int j = 0; j < 2; ++j)
#pragma unroll
                    for (int r2 = 0; r2 < 4; ++r2) ps[mi2][j][r2] = 0.f;
        }
#pragma unroll
        for (int mi2 = 0; mi2 < 2; ++mi2) {
            const int m = ph * 2 + mi2;
            float g[4];
#pragma unroll
            for (int r2 = 0; r2 < 4; ++r2) {
                float v = ahh[mi2][r2] + (ahl[mi2][r2] + alh[mi2][r2]);
                float u2 = 1.5957691216057308f * (v + 0.044715f * v * v * v);
                float t = 1.0f - 2.0f / (1.0f + __expf(u2));
                g[r2] = 0.5f * v * (1.0f + t);
            }
            if (!LAST) {
                int o = wn * 16 + fr;
                int nb = n0 + m * 16 + kg * 4;
                size_t di = ((size_t)(b * 128 + o) << 14) + (nb >> 1);
                uint2v hv = { pack_hi(g[0], g[1]), pack_hi(g[2], g[3]) };
                uint2v lv = { pack_hi(resid(g[0]), resid(g[1])), pack_hi(resid(g[2]), resid(g[3])) };
                *(uint2v*)(hfTh + di) = hv;
                *(uint2v*)(hfTl + di) = lv;
            } else {
#pragma unroll
                for (int r2 = 0; r2 < 4; ++r2) {
                    ps[mi2][0][r2] += g[r2] * w0v;
                    ps[mi2][1][r2] += g[r2] * w1v;
                }
            }
        }

        if (LAST) {
#pragma unroll
            for (int mi2 = 0; mi2 < 2; ++mi2)
#pragma unroll
                for (int j = 0; j < 2; ++j)
#pragma unroll
                    for (int r2 = 0; r2 < 4; ++r2) {
                        float v = ps[mi2][j][r2];
                        v += __shfl_xor(v, 1);
                        v += __shfl_xor(v, 2);
                        v += __shfl_xor(v, 4);
                        v += __shfl_xor(v, 8);
                        ps[mi2][j][r2] = v;
                    }
            if (fr == 0) {
#pragma unroll
                for (int mi2 = 0; mi2 < 2; ++mi2)
#pragma unroll
                    for (int r2 = 0; r2 < 4; ++r2) {
                        redo[wn][mi2 * 16 + kg * 4 + r2][0] = ps[mi2][0][r2];
                        redo[wn][mi2 * 16 + kg * 4 + r2][1] = ps[mi2][1][r2];
                    }
            }
            LBAR();
            if (tid < 64) {
                int nl = tid >> 1, j = tid & 1;
                float val = ob[j];
#pragma unroll
                for (int w8 = 0; w8 < 8; ++w8) val += redo[w8][nl][j];
                u[((size_t)((b << 15) + n0 + ph * 32 + nl)) * 2 + j] = val;
            }
            LBAR();
        }
    }
}

extern "C" void kernel_launch(void* const* d_in, const int* in_sizes, int n_in,
                              void* d_out, int out_size, void* d_ws, size_t ws_size,
                              hipStream_t stream) {
    const float* a        = (const float*)d_in[0];
    const float* x        = (const float*)d_in[1];
    const float* y        = (const float*)d_in[2];
    const float* fc_in_w  = (const float*)d_in[3];
    const float* fc_in_b  = (const float*)d_in[4];
    const float* freqs    = (const float*)d_in[5];
    const float* w_real   = (const float*)d_in[6];
    const float* w_imag   = (const float*)d_in[7];
    const float* fc_out_w = (const float*)d_in[8];
    const float* fc_out_b = (const float*)d_in[9];
    float* out = (float*)d_out;

    uint_t* ws    = (uint_t*)d_ws;
    uint_t* hfTh  = ws;                                        // B*C*N/2 = 4,194,304 dwords
    uint_t* hfTl  = hfTh + (size_t)Bb * Cc * Nn / 2;           // 4,194,304
    float*  Spart = (float*)(hfTl + (size_t)Bb * Cc * Nn / 2); // B*2*SKN*PS = 8,421,376 floats
    float*  S     = Spart + (size_t)Bb * 2 * SKN * PS;         // 65,536
    uint_t* Gh    = (uint_t*)(S + (size_t)Bb * 2 * Cc * Ff);   // 32,768
    uint_t* Gl    = Gh + (size_t)Bb * Cc * Ff;                 // 32,768
    float*  xT    = (float*)(Gl + (size_t)Bb * Cc * Ff);       // 196,608 floats
    float*  yT    = xT + (size_t)Bb * 3 * Nn;                  // 196,608

    prep_xt<<<(Bb * Nn) / 256, 256, 0, stream>>>(x, y, xT, yT);
    in_proj<<<(Bb * Cc * Nn / 2) / 256, 256, 0, stream>>>(a, fc_in_w, fc_in_b, hfTh, hfTl);

    // layer 0 forward (from in_proj's hfT), 128 split-K slots
    fwd_lds<<<dim3(SKN, Bb), 512, 0, stream>>>(hfTh, hfTl, xT, freqs, Spart);
    reduce_kernel<<<dim3(256, 4), 256, 0, stream>>>(Spart, S);
    mix_kernel<<<dim3(64, 8), 256, 0, stream>>>(S, w_real, w_imag, Gh, Gl);

    // layers 0..2: fused inverse(l) + forward(l+1); hfT never touches global
    for (int l = 0; l < LL - 1; ++l) {
        const float* kI  = freqs  + (size_t)l * Ff * 3;
        const float* kF  = freqs  + (size_t)(l + 1) * Ff * 3;
        const float* Wre = w_real + (size_t)(l + 1) * Cc * Cc * Ff;
        const float* Wim = w_imag + (size_t)(l + 1) * Cc * Cc * Ff;

        inv_fwd<<<dim3(128, Bb), 512, 0, stream>>>(Gh, Gl, xT, kI, kF, Spart);
        reduce_kernel<<<dim3(256, 4), 256, 0, stream>>>(Spart, S);
        mix_kernel<<<dim3(64, 8), 256, 0, stream>>>(S, Wre, Wim, Gh, Gl);
    }

    // final inverse at y + fused out-projection
    inv_reg<1><<<dim3(512, Bb), 512, 0, stream>>>(Gh, Gl, yT, freqs + (size_t)(LL - 1) * Ff * 3,
                                                  hfTh, hfTl, fc_out_w, fc_out_b, out);
}